// Round 7
// baseline (162.080 us; speedup 1.0000x reference)
//
#include <hip/hip_runtime.h>

typedef _Float16 f16;
typedef _Float16 f16x8 __attribute__((ext_vector_type(8)));
typedef float f32x4 __attribute__((ext_vector_type(4)));

#define MFMA16(a, b, c) __builtin_amdgcn_mfma_f32_16x16x32_f16((a), (b), (c), 0, 0, 0)

constexpr int SEQ   = 16;
constexpr int PLEN  = 15;
constexpr int BATCH = 32768;
constexpr int POSE  = 34;
constexpr int HD    = 64;
constexpr int GRPS  = 4;     // four independent 16-row chains per wave (in-wave ILP)
constexpr int ROWS  = 16;    // rows per chain
constexpr int BROWS = GRPS * ROWS;  // 64 rows per block
constexpr int XROW  = 136;   // [h 0..63 | x 64..97 | 1.0 @98 | 0..127 | pad]

constexpr float LOG2E  = 1.4426950408889634f;
constexpr float LOG2E2 = 2.8853900817779268f;

__device__ __forceinline__ float rcpf(float x)   { return __builtin_amdgcn_rcpf(x); }
__device__ __forceinline__ float exp2f_(float x) { return __builtin_amdgcn_exp2f(x); }

__global__ __launch_bounds__(256, 2)
void lstm7(const float* __restrict__ obs,
           const float* __restrict__ Wih_e, const float* __restrict__ Whh_e,
           const float* __restrict__ b_e,
           const float* __restrict__ Wih_d, const float* __restrict__ Whh_d,
           const float* __restrict__ b_d,
           const float* __restrict__ fc_w, const float* __restrict__ fc_b,
           float* __restrict__ out)
{
    // [dbuf][chain][row][XROW] — 34816 B
    __shared__ f16 bfr[2 * GRPS * ROWS * XROW];

    const int tid  = threadIdx.x;
    const int lane = tid & 63;
    const int q    = tid >> 6;     // gate-column split: j = q*16 + l15
    const int l15  = lane & 15;
    const int l4   = lane >> 4;
    const int blkbase = blockIdx.x * BROWS;

    f16x8 Bw[4][4];   // [gate i/f/g/o][kf]
    float be[4];      // fused-decoder bias (acc init), else unused
    auto loadB = [&](const float* __restrict__ Wih, const float* __restrict__ Whh,
                     const float* __restrict__ b) {
        #pragma unroll
        for (int gg = 0; gg < 4; ++gg) {
            const int r = (gg * 4 + q) * 16 + l15;
            const float sc = (gg == 2) ? LOG2E2 : LOG2E;
            #pragma unroll
            for (int kf = 0; kf < 2; ++kf) {
                const float* src = Whh + r * HD + kf * 32 + l4 * 8;
                #pragma unroll
                for (int j = 0; j < 8; ++j) Bw[gg][kf][j] = (f16)(src[j] * sc);
            }
            {
                const float* src = Wih + r * POSE + l4 * 8;
                #pragma unroll
                for (int j = 0; j < 8; ++j) Bw[gg][2][j] = (f16)(src[j] * sc);
            }
            #pragma unroll
            for (int j = 0; j < 8; ++j) {
                const int k = 96 + l4 * 8 + j;
                float v = 0.f;
                if (k < 98)       v = Wih[r * POSE + (k - 64)];
                else if (k == 98) v = b[r];
                Bw[gg][3][j] = (f16)(v * sc);
            }
        }
    };

    // fused decoder weights: W_eff = Whh_d + Wih_d @ fc_w ; b_eff = b_d + Wih_d @ fc_b
    auto loadBeff = [&]() {
        #pragma unroll
        for (int gg = 0; gg < 4; ++gg) {
            const int r = (gg * 4 + q) * 16 + l15;
            const float sc = (gg == 2) ? LOG2E2 : LOG2E;
            #pragma unroll
            for (int kf = 0; kf < 2; ++kf) {
                float a8[8];
                const float* wh = Whh_d + r * HD + kf * 32 + l4 * 8;
                #pragma unroll
                for (int j = 0; j < 8; ++j) a8[j] = wh[j];
                for (int pp = 0; pp < POSE; ++pp) {
                    const float wp = Wih_d[r * POSE + pp];
                    const float* fw = fc_w + pp * HD + kf * 32 + l4 * 8;
                    #pragma unroll
                    for (int j = 0; j < 8; ++j) a8[j] += wp * fw[j];
                }
                #pragma unroll
                for (int j = 0; j < 8; ++j) Bw[gg][kf][j] = (f16)(a8[j] * sc);
            }
            float bb = b_d[r];
            for (int pp = 0; pp < POSE; ++pp) bb += Wih_d[r * POSE + pp] * fc_b[pp];
            be[gg] = bb * sc;
        }
    };

    auto stage_x = [&](int ts, int dstbuf) {
        const float* src = obs + ((size_t)ts * BATCH + blkbase) * POSE;  // 2176 contiguous f32
        #pragma unroll
        for (int it = 0; it < 9; ++it) {
            int i = it * 256 + tid;
            if (i < BROWS * POSE) {
                int row = i / POSE, col = i - row * POSE;
                bfr[((dstbuf * GRPS + (row >> 4)) * ROWS + (row & 15)) * XROW + HD + col] = (f16)src[i];
            }
        }
    };

    // fc weights / bias, register-resident
    const int  p    = q * 16 + l15;
    const bool fcok = (q < 3);
    f16x8 Bfc[2];
    #pragma unroll
    for (int kf = 0; kf < 2; ++kf)
        #pragma unroll
        for (int j = 0; j < 8; ++j)
            Bfc[kf][j] = (f16)((fcok && p < POSE) ? fc_w[p * HD + kf * 32 + l4 * 8 + j] : 0.f);
    const float fcb = (fcok && p < POSE) ? fc_b[p] : 0.f;

    loadB(Wih_e, Whh_e, b_e);

    // init: h0 = 0, bias col = 1.0 (both buffers)
    for (int i = tid; i < 2 * GRPS * ROWS * XROW; i += 256) {
        int c = i % XROW;
        bfr[i] = (c == 98) ? (f16)1.0f : (f16)0.0f;
    }
    __syncthreads();
    stage_x(0, 0);
    __syncthreads();

    f32x4 cst[GRPS];
    #pragma unroll
    for (int c = 0; c < GRPS; ++c) cst[c] = (f32x4)0.f;

    auto ldA = [&](int c, int sb, f16x8 (&a)[4], int nkf) {
        for (int kf = 0; kf < nkf; ++kf)
            a[kf] = *(const f16x8*)&bfr[((sb * GRPS + c) * ROWS + l15) * XROW + kf * 32 + l4 * 8];
    };
    auto g128 = [&](const f16x8 (&a)[4], f32x4 (&acc)[4]) {
        #pragma unroll
        for (int gg = 0; gg < 4; ++gg) acc[gg] = (f32x4)0.f;
        #pragma unroll
        for (int kf = 0; kf < 4; ++kf)
            #pragma unroll
            for (int gg = 0; gg < 4; ++gg) acc[gg] = MFMA16(a[kf], Bw[gg][kf], acc[gg]);
    };
    auto g64 = [&](const f16x8 (&a)[4], f32x4 (&acc)[4]) {
        #pragma unroll
        for (int gg = 0; gg < 4; ++gg) acc[gg] = (f32x4){be[gg], be[gg], be[gg], be[gg]};
        #pragma unroll
        for (int kf = 0; kf < 2; ++kf)
            #pragma unroll
            for (int gg = 0; gg < 4; ++gg) acc[gg] = MFMA16(a[kf], Bw[gg][kf], acc[gg]);
    };
    auto nonlin = [&](int c, f32x4 (&acc)[4], int db) {
        #pragma unroll
        for (int r = 0; r < 4; ++r) {
            float si = rcpf(1.f + exp2f_(-acc[0][r]));
            float sf = rcpf(1.f + exp2f_(-acc[1][r]));
            float tg = 1.f - 2.f * rcpf(1.f + exp2f_(acc[2][r]));
            float so = rcpf(1.f + exp2f_(-acc[3][r]));
            float cc = sf * cst[c][r] + si * tg;
            float tc = 1.f - 2.f * rcpf(1.f + exp2f_(cc * LOG2E2));
            cst[c][r] = cc;
            bfr[((db * GRPS + c) * ROWS + l4 * 4 + r) * XROW + q * 16 + l15] = (f16)(so * tc);
        }
    };
    auto fcst = [&](int c, int sb, int t) {   // out[t] = fc(h in buf[sb], chain c)
        if (!fcok) return;
        f16x8 ah[2];
        #pragma unroll
        for (int kf = 0; kf < 2; ++kf)
            ah[kf] = *(const f16x8*)&bfr[((sb * GRPS + c) * ROWS + l15) * XROW + kf * 32 + l4 * 8];
        f32x4 o = {fcb, fcb, fcb, fcb};
        o = MFMA16(ah[0], Bfc[0], o);
        o = MFMA16(ah[1], Bfc[1], o);
        if (p < POSE) {
            float* ob = out + ((size_t)t * BATCH + blkbase + c * ROWS) * POSE;
            #pragma unroll
            for (int r = 0; r < 4; ++r) ob[(l4 * 4 + r) * POSE + p] = o[r];
        }
    };

    int cur = 0;

    // ======== encoder: 16 steps, staggered 4-chain schedule, 1 barrier/step ========
    #pragma unroll 1
    for (int s = 0; s < SEQ; ++s) {
        const int nxt = cur ^ 1;
        f16x8 a[GRPS][4];
        f32x4 acc[GRPS][4];
        ldA(0, cur, a[0], 4); g128(a[0], acc[0]);
        ldA(1, cur, a[1], 4); g128(a[1], acc[1]);
        nonlin(0, acc[0], nxt);
        ldA(2, cur, a[2], 4); g128(a[2], acc[2]);
        nonlin(1, acc[1], nxt);
        ldA(3, cur, a[3], 4); g128(a[3], acc[3]);
        { int ts = s + 1 < 15 ? s + 1 : 15; stage_x(ts, nxt); }
        nonlin(2, acc[2], nxt);
        nonlin(3, acc[3], nxt);
        __syncthreads();
        cur = nxt;
    }

    // ======== decoder step 0: original dec weights, K=128, x = obs[15] ========
    loadB(Wih_d, Whh_d, b_d);
    {
        const int nxt = cur ^ 1;
        f16x8 a[GRPS][4];
        f32x4 acc[GRPS][4];
        ldA(0, cur, a[0], 4); g128(a[0], acc[0]);
        ldA(1, cur, a[1], 4); g128(a[1], acc[1]);
        nonlin(0, acc[0], nxt);
        ldA(2, cur, a[2], 4); g128(a[2], acc[2]);
        nonlin(1, acc[1], nxt);
        ldA(3, cur, a[3], 4); g128(a[3], acc[3]);
        nonlin(2, acc[2], nxt);
        nonlin(3, acc[3], nxt);
        __syncthreads();
        cur = nxt;
    }

    // switch to fused decoder recurrence (K=64, bias via be[], no x, no feedback)
    loadBeff();

    // ======== decoder steps 1..14: 1 barrier/step; fc(h_{t-1}) interleaved ========
    #pragma unroll 1
    for (int t = 1; t < PLEN; ++t) {
        const int nxt = cur ^ 1;
        f16x8 a[GRPS][4];
        f32x4 acc[GRPS][4];
        ldA(0, cur, a[0], 2); g64(a[0], acc[0]);
        ldA(1, cur, a[1], 2); g64(a[1], acc[1]);
        fcst(0, cur, t - 1);
        nonlin(0, acc[0], nxt);
        ldA(2, cur, a[2], 2); g64(a[2], acc[2]);
        fcst(1, cur, t - 1);
        nonlin(1, acc[1], nxt);
        ldA(3, cur, a[3], 2); g64(a[3], acc[3]);
        fcst(2, cur, t - 1);
        nonlin(2, acc[2], nxt);
        fcst(3, cur, t - 1);
        nonlin(3, acc[3], nxt);
        __syncthreads();
        cur = nxt;
    }
    // final outputs: fc(h_14)
    fcst(0, cur, PLEN - 1);
    fcst(1, cur, PLEN - 1);
    fcst(2, cur, PLEN - 1);
    fcst(3, cur, PLEN - 1);
}

extern "C" void kernel_launch(void* const* d_in, const int* in_sizes, int n_in,
                              void* d_out, int out_size, void* d_ws, size_t ws_size,
                              hipStream_t stream) {
    const float* obs   = (const float*)d_in[0];
    const float* Wih_e = (const float*)d_in[1];
    const float* Whh_e = (const float*)d_in[2];
    const float* b_e   = (const float*)d_in[3];
    const float* Wih_d = (const float*)d_in[4];
    const float* Whh_d = (const float*)d_in[5];
    const float* b_d   = (const float*)d_in[6];
    const float* fc_w  = (const float*)d_in[7];
    const float* fc_b  = (const float*)d_in[8];
    float* out = (float*)d_out;

    lstm7<<<dim3(BATCH / BROWS), dim3(256), 0, stream>>>(
        obs, Wih_e, Whh_e, b_e, Wih_d, Whh_d, b_d, fc_w, fc_b, out);
}